// Round 7
// baseline (375.837 us; speedup 1.0000x reference)
//
#include <hip/hip_runtime.h>
#include <stdint.h>

typedef __bf16 bf16;
typedef __bf16 bf16x4 __attribute__((ext_vector_type(4)));
typedef __bf16 bf16x8 __attribute__((ext_vector_type(8)));
typedef short short4v __attribute__((ext_vector_type(4)));
typedef float floatx4 __attribute__((ext_vector_type(4)));

#define MFMA32(a, b, c) __builtin_amdgcn_mfma_f32_16x16x32_bf16((a), (b), (c), 0, 0, 0)

__device__ __forceinline__ floatx4 mfma16(bf16x4 a, bf16x4 b, floatx4 c) {
  return __builtin_amdgcn_mfma_f32_16x16x16bf16_1k(
      __builtin_bit_cast(short4v, a), __builtin_bit_cast(short4v, b), c, 0, 0, 0);
}

__device__ __forceinline__ void gload16(const void* g, void* l) {
  __builtin_amdgcn_global_load_lds(
      (const __attribute__((address_space(1))) void*)g,
      (__attribute__((address_space(3))) void*)l, 16, 0, 0);
}

__device__ __forceinline__ bf16x8 load8(const float* p) {
  float4 lo = *(const float4*)p;
  float4 hi = *(const float4*)(p + 4);
  bf16x8 r;
  r[0] = (bf16)lo.x; r[1] = (bf16)lo.y; r[2] = (bf16)lo.z; r[3] = (bf16)lo.w;
  r[4] = (bf16)hi.x; r[5] = (bf16)hi.y; r[6] = (bf16)hi.z; r[7] = (bf16)hi.w;
  return r;
}

// One launch converting x, Wq, Wo to bf16. grid (2048, 3), 8 elems/thread.
__global__ __launch_bounds__(256) void conv3(const float* __restrict__ a, bf16* __restrict__ ab,
                                             const float* __restrict__ b, bf16* __restrict__ bb,
                                             const float* __restrict__ c, bf16* __restrict__ cb) {
  const int i = blockIdx.x * 256 + threadIdx.x;
  const float* src = blockIdx.y == 0 ? a : (blockIdx.y == 1 ? b : c);
  bf16* dst = blockIdx.y == 0 ? ab : (blockIdx.y == 1 ? bb : cb);
  ((bf16x8*)dst)[i] = load8(src + (size_t)i * 8);
}

// Pack K (f32->bf16) and transpose-pack V: Vf[t][64] -> Vtb[d][2048].
__global__ __launch_bounds__(256) void pack_kv(const float* __restrict__ Kf,
                                               const float* __restrict__ Vf,
                                               bf16* __restrict__ Kb,
                                               bf16* __restrict__ Vtb) {
  int i = blockIdx.x * 256 + threadIdx.x;
  if (i < 2048 * 64) {
    Kb[i] = (bf16)Kf[i];
    const int t = i >> 6, d = i & 63;
    Vtb[(size_t)d * 2048 + t] = (bf16)Vf[i];
  }
}

// C[M,N] = A[M,K] @ B[N,K]^T, bf16 in, dbuf global_load_lds staging.
// 64x128 C-tile -> 512 blocks = 2 blocks/CU co-resident (R6: helped ~8us/gemm).
template <typename TC>
__global__ __launch_bounds__(256) void gemm_bt_a(const bf16* __restrict__ A,
                                                 const bf16* __restrict__ B,
                                                 TC* __restrict__ C,
                                                 int M, int N, int K) {
  __shared__ __align__(16) bf16 As[2][64 * 32];
  __shared__ __align__(16) bf16 Bs[2][128 * 32];
  const int tid = threadIdx.x;
  const int wave = tid >> 6, lane = tid & 63;
  const int quad = lane >> 4, l16 = lane & 15;
  const int m0 = blockIdx.y * 64, n0 = blockIdx.x * 128;
  const int wm = (wave >> 1) * 32, wn = (wave & 1) * 64;

  floatx4 acc[2][4];
#pragma unroll
  for (int i = 0; i < 2; i++)
#pragma unroll
    for (int j = 0; j < 4; j++) acc[i][j] = (floatx4)0.f;

  const int srow = tid >> 2, scol = (tid & 3) * 8;
  const bf16* Ap = A + (size_t)(m0 + srow) * K + scol;
  const bf16* Bp = B + (size_t)(n0 + srow) * K + scol;

  auto stage = [&](int k0, int buf) {
    gload16(Ap + k0, (char*)As[buf] + tid * 16);
    gload16(Bp + k0, (char*)Bs[buf] + tid * 16);
    gload16(Bp + (size_t)64 * K + k0, (char*)Bs[buf] + 4096 + tid * 16);
  };
  auto compute = [&](int buf) {
    bf16x8 af[2], bfr[4];
#pragma unroll
    for (int mt = 0; mt < 2; mt++)
      af[mt] = *(const bf16x8*)(&As[buf][(wm + mt * 16 + l16) * 32 + quad * 8]);
#pragma unroll
    for (int nt = 0; nt < 4; nt++)
      bfr[nt] = *(const bf16x8*)(&Bs[buf][(wn + nt * 16 + l16) * 32 + quad * 8]);
#pragma unroll
    for (int mt = 0; mt < 2; mt++)
#pragma unroll
      for (int nt = 0; nt < 4; nt++)
        acc[mt][nt] = MFMA32(af[mt], bfr[nt], acc[mt][nt]);
  };

  stage(0, 0);
  for (int k0 = 0; k0 < K; k0 += 64) {
    __syncthreads();
    if (k0 + 32 < K) stage(k0 + 32, 1);
    compute(0);
    __syncthreads();
    if (k0 + 64 < K) stage(k0 + 64, 0);
    compute(1);
  }

#pragma unroll
  for (int mt = 0; mt < 2; mt++) {
#pragma unroll
    for (int nt = 0; nt < 4; nt++) {
      const int col = n0 + wn + nt * 16 + l16;
      const int row = m0 + wm + mt * 16 + quad * 4;
#pragma unroll
      for (int r = 0; r < 4; r++)
        C[(size_t)(row + r) * N + col] = (TC)acc[mt][nt][r];
    }
  }
}

// Fused K+V projection, split-K x8. A = xb (bf16), B = Wk/Wv (f32 -> bf16).
__global__ __launch_bounds__(256) void kv_gemm(const bf16* __restrict__ xb,
                                               const float* __restrict__ Wk,
                                               const float* __restrict__ Wv,
                                               float* __restrict__ Kf,
                                               float* __restrict__ Vf) {
  __shared__ __align__(16) bf16 As[128 * 40];
  __shared__ __align__(16) bf16 Bs[128 * 40];
  const int tid = threadIdx.x;
  const int wave = tid >> 6, lane = tid & 63;
  const int quad = lane >> 4, l16 = lane & 15;
  const int m0 = blockIdx.y * 128;
  const int kbeg = blockIdx.x * 256, kend = kbeg + 256;
  const int wm = (wave >> 1) * 64, wn = (wave & 1) * 64;

  floatx4 acc[4][4];
#pragma unroll
  for (int i = 0; i < 4; i++)
#pragma unroll
    for (int j = 0; j < 4; j++) acc[i][j] = (floatx4)0.f;

  const int sr = tid >> 2, sc = (tid & 3) * 8;

  for (int k0 = kbeg; k0 < kend; k0 += 32) {
    __syncthreads();
#pragma unroll
    for (int rr = 0; rr < 2; rr++) {
      const int row = sr + rr * 64;
      *(bf16x8*)(&As[row * 40 + sc]) =
          *(const bf16x8*)(&xb[(size_t)(m0 + row) * 2048 + k0 + sc]);
      const float* bsrc = (row < 64) ? &Wk[(size_t)row * 2048 + k0 + sc]
                                     : &Wv[(size_t)(row - 64) * 2048 + k0 + sc];
      *(bf16x8*)(&Bs[row * 40 + sc]) = load8(bsrc);
    }
    __syncthreads();

    bf16x8 af[4], bfr[4];
#pragma unroll
    for (int mt = 0; mt < 4; mt++)
      af[mt] = *(const bf16x8*)(&As[(wm + mt * 16 + l16) * 40 + quad * 8]);
#pragma unroll
    for (int nt = 0; nt < 4; nt++)
      bfr[nt] = *(const bf16x8*)(&Bs[(wn + nt * 16 + l16) * 40 + quad * 8]);
#pragma unroll
    for (int mt = 0; mt < 4; mt++)
#pragma unroll
      for (int nt = 0; nt < 4; nt++)
        acc[mt][nt] = MFMA32(af[mt], bfr[nt], acc[mt][nt]);
  }

#pragma unroll
  for (int mt = 0; mt < 4; mt++) {
#pragma unroll
    for (int nt = 0; nt < 4; nt++) {
      const int col = wn + nt * 16 + l16;
      const int row = m0 + wm + mt * 16 + quad * 4;
      float* dst = (col < 64) ? &Kf[(size_t)row * 64 + col]
                              : &Vf[(size_t)row * 64 + (col - 64)];
#pragma unroll
      for (int r = 0; r < 4; r++) atomicAdd(dst + (size_t)r * 64, acc[mt][nt][r]);
    }
  }
}

// Flash attention, S^T orientation, max-free softmax, NO LDS / NO BARRIERS:
// K and V^T fragments are loaded directly from global in MFMA layout (KV is
// 512 KB -> L2-resident, hot across 32 heads). Waves run as independent
// streams; latency hidden by 8 waves/CU without barrier lock-step.
// Grid (16 pairs, 32 heads): block runs q-tiles (bx, 31-bx) -> exactly 33
// k-tile iters per block, perfectly balanced per CU (R6 lesson: balance
// dominates; same-bx stacking on a CU cost 1.5x).
__global__ __launch_bounds__(256) void attn_kernel(const bf16* __restrict__ Q,
                                                   const bf16* __restrict__ Kb,
                                                   const bf16* __restrict__ Vtb,
                                                   bf16* __restrict__ O) {
  const int tid = threadIdx.x;
  const int wq = tid >> 6, lane = tid & 63;
  const int quad = lane >> 4, l16 = lane & 15;
  const int h = blockIdx.y;
  const float scale2 = 0.125f * 1.44269504f;
  const float slope2 = exp2f(-0.25f * (float)(h + 1)) * 1.44269504f;

  float cq[4];
#pragma unroll
  for (int r = 0; r < 4; r++) cq[r] = slope2 * (float)(quad * 4 + r);
  const float s16 = slope2 * 16.f;
  const bf16x4 ones = {(bf16)1.f, (bf16)1.f, (bf16)1.f, (bf16)1.f};

  auto run_tile = [&](int t) {
    const int qi = t * 64 + wq * 16 + l16;  // this lane's query row
    bf16x8 qf[2];
#pragma unroll
    for (int kk = 0; kk < 2; kk++)
      qf[kk] = *(const bf16x8*)(&Q[(size_t)qi * 2048 + h * 64 + kk * 32 + quad * 8]);

    floatx4 oacc[4];
#pragma unroll
    for (int dt = 0; dt < 4; dt++) oacc[dt] = (floatx4)0.f;
    floatx4 lacc = (floatx4)0.f;

    for (int kt = 0; kt <= t; kt++) {
      const int k0 = kt * 64;

      // S^T[key][q] = K · Q^T ; A-frags straight from global (L2-hot)
      floatx4 s[4];
#pragma unroll
      for (int mt = 0; mt < 4; mt++) s[mt] = (floatx4)0.f;
      bf16x8 kf[2][4];
#pragma unroll
      for (int kk = 0; kk < 2; kk++)
#pragma unroll
        for (int mt = 0; mt < 4; mt++)
          kf[kk][mt] = *(const bf16x8*)(&Kb[(size_t)(k0 + mt * 16 + l16) * 64 +
                                            kk * 32 + quad * 8]);
      // V^T fragments for PV (independent of S chain -> issue early)
      bf16x4 va[4][4];
#pragma unroll
      for (int dt = 0; dt < 4; dt++)
#pragma unroll
        for (int mt = 0; mt < 4; mt++)
          va[dt][mt] = *(const bf16x4*)(&Vtb[(size_t)(dt * 16 + l16) * 2048 +
                                             k0 + mt * 16 + quad * 4]);
#pragma unroll
      for (int kk = 0; kk < 2; kk++)
#pragma unroll
        for (int mt = 0; mt < 4; mt++) s[mt] = MFMA32(kf[kk][mt], qf[kk], s[mt]);

      // p = exp2(s*scale2 + slope2*(j-i)); bounded -> no running max needed
      const float base0 = slope2 * (float)(k0 - qi);
      bf16x4 pb[4];
      if (kt < t) {  // interior: no mask
        float base = base0;
#pragma unroll
        for (int mt = 0; mt < 4; mt++) {
          bf16x4 tb;
#pragma unroll
          for (int r = 0; r < 4; r++)
            tb[r] = (bf16)exp2f(__builtin_fmaf(s[mt][r], scale2, base + cq[r]));
          pb[mt] = tb;
          base += s16;
        }
      } else {  // diagonal tile: causal mask
        const int qloc = qi - k0;  // in [0,63]
        float base = base0;
#pragma unroll
        for (int mt = 0; mt < 4; mt++) {
          bf16x4 tb;
#pragma unroll
          for (int r = 0; r < 4; r++) {
            const int moff = mt * 16 + quad * 4 + r;
            const float p = exp2f(__builtin_fmaf(s[mt][r], scale2, base + cq[r]));
            tb[r] = (moff <= qloc) ? (bf16)p : (bf16)0.f;
          }
          pb[mt] = tb;
          base += s16;
        }
      }

      // O^T[d][q] += V^T · P^T ; l += 1 · P^T (matrix-pipe row-sum)
#pragma unroll
      for (int mt = 0; mt < 4; mt++) {
        lacc = mfma16(ones, pb[mt], lacc);
#pragma unroll
        for (int dt = 0; dt < 4; dt++)
          oacc[dt] = mfma16(va[dt][mt], pb[mt], oacc[dt]);
      }
    }

    const float linv = 1.0f / lacc[0];
#pragma unroll
    for (int dt = 0; dt < 4; dt++) {
      bf16x4 ob;
#pragma unroll
      for (int r = 0; r < 4; r++) ob[r] = (bf16)(oacc[dt][r] * linv);
      *(bf16x4*)(&O[(size_t)qi * 2048 + h * 64 + dt * 16 + quad * 4]) = ob;
    }
  };

  run_tile(31 - blockIdx.x);  // long tile first
  run_tile(blockIdx.x);       // 33 iters total, all blocks equal
}

extern "C" void kernel_launch(void* const* d_in, const int* in_sizes, int n_in,
                              void* d_out, int out_size, void* d_ws,
                              size_t ws_size, hipStream_t stream) {
  (void)in_sizes; (void)n_in; (void)out_size; (void)ws_size;
  const float* x = (const float*)d_in[0];
  const float* Wq = (const float*)d_in[1];
  const float* Wk = (const float*)d_in[2];
  const float* Wv = (const float*)d_in[3];
  const float* Wo = (const float*)d_in[4];
  float* out = (float*)d_out;

  const size_t NE = (size_t)2048 * 2048;
  bf16* xb = (bf16*)d_ws;              // 8 MB (reused as AO after Q-proj)
  bf16* Wqb = xb + NE;                 // 8 MB
  bf16* Wob = Wqb + NE;                // 8 MB
  bf16* Qb = Wob + NE;                 // 8 MB
  float* Kf = (float*)(Qb + NE);       // 512 KB
  float* Vf = Kf + 2048 * 64;          // 512 KB
  bf16* Kb = (bf16*)(Vf + 2048 * 64);  // 256 KB
  bf16* Vtb = Kb + 2048 * 64;          // 256 KB
  bf16* AO = xb;

  hipMemsetAsync(Kf, 0, 2 * 2048 * 64 * sizeof(float), stream);
  conv3<<<dim3(2048, 3), 256, 0, stream>>>(x, xb, Wq, Wqb, Wo, Wob);
  gemm_bt_a<bf16><<<dim3(16, 32), 256, 0, stream>>>(xb, Wqb, Qb, 2048, 2048, 2048);
  kv_gemm<<<dim3(8, 16), 256, 0, stream>>>(xb, Wk, Wv, Kf, Vf);
  pack_kv<<<512, 256, 0, stream>>>(Kf, Vf, Kb, Vtb);
  attn_kernel<<<dim3(16, 32), 256, 0, stream>>>(Qb, Kb, Vtb, AO);
  gemm_bt_a<float><<<dim3(16, 32), 256, 0, stream>>>(AO, Wob, out, 2048, 2048, 2048);
}

// Round 8
// 244.332 us; speedup vs baseline: 1.5382x; 1.5382x over previous
//
#include <hip/hip_runtime.h>
#include <stdint.h>

typedef __bf16 bf16;
typedef __bf16 bf16x4 __attribute__((ext_vector_type(4)));
typedef __bf16 bf16x8 __attribute__((ext_vector_type(8)));
typedef short short4v __attribute__((ext_vector_type(4)));
typedef float floatx4 __attribute__((ext_vector_type(4)));

#define MFMA32(a, b, c) __builtin_amdgcn_mfma_f32_16x16x32_bf16((a), (b), (c), 0, 0, 0)

__device__ __forceinline__ floatx4 mfma16(bf16x4 a, bf16x4 b, floatx4 c) {
  return __builtin_amdgcn_mfma_f32_16x16x16bf16_1k(
      __builtin_bit_cast(short4v, a), __builtin_bit_cast(short4v, b), c, 0, 0, 0);
}

__device__ __forceinline__ void gload16(const void* g, void* l) {
  __builtin_amdgcn_global_load_lds(
      (const __attribute__((address_space(1))) void*)g,
      (__attribute__((address_space(3))) void*)l, 16, 0, 0);
}

__device__ __forceinline__ bf16x8 load8(const float* p) {
  float4 lo = *(const float4*)p;
  float4 hi = *(const float4*)(p + 4);
  bf16x8 r;
  r[0] = (bf16)lo.x; r[1] = (bf16)lo.y; r[2] = (bf16)lo.z; r[3] = (bf16)lo.w;
  r[4] = (bf16)hi.x; r[5] = (bf16)hi.y; r[6] = (bf16)hi.z; r[7] = (bf16)hi.w;
  return r;
}

// One launch converting x, Wq, Wo to bf16. grid (2048, 3), 8 elems/thread.
__global__ __launch_bounds__(256) void conv3(const float* __restrict__ a, bf16* __restrict__ ab,
                                             const float* __restrict__ b, bf16* __restrict__ bb,
                                             const float* __restrict__ c, bf16* __restrict__ cb) {
  const int i = blockIdx.x * 256 + threadIdx.x;
  const float* src = blockIdx.y == 0 ? a : (blockIdx.y == 1 ? b : c);
  bf16* dst = blockIdx.y == 0 ? ab : (blockIdx.y == 1 ? bb : cb);
  ((bf16x8*)dst)[i] = load8(src + (size_t)i * 8);
}

// Pack K (f32->bf16) and transpose-pack V: Vf[t][64] -> Vtb[d][2048].
__global__ __launch_bounds__(256) void pack_kv(const float* __restrict__ Kf,
                                               const float* __restrict__ Vf,
                                               bf16* __restrict__ Kb,
                                               bf16* __restrict__ Vtb) {
  int i = blockIdx.x * 256 + threadIdx.x;
  if (i < 2048 * 64) {
    Kb[i] = (bf16)Kf[i];
    const int t = i >> 6, d = i & 63;
    Vtb[(size_t)d * 2048 + t] = (bf16)Vf[i];
  }
}

// C[M,N] = A[M,K] @ B[N,K]^T, bf16 in, dbuf global_load_lds staging.
// 64x128 C-tile -> 512 blocks = 2 blocks/CU co-resident (R6 validated).
template <typename TC>
__global__ __launch_bounds__(256) void gemm_bt_a(const bf16* __restrict__ A,
                                                 const bf16* __restrict__ B,
                                                 TC* __restrict__ C,
                                                 int M, int N, int K) {
  __shared__ __align__(16) bf16 As[2][64 * 32];
  __shared__ __align__(16) bf16 Bs[2][128 * 32];
  const int tid = threadIdx.x;
  const int wave = tid >> 6, lane = tid & 63;
  const int quad = lane >> 4, l16 = lane & 15;
  const int m0 = blockIdx.y * 64, n0 = blockIdx.x * 128;
  const int wm = (wave >> 1) * 32, wn = (wave & 1) * 64;

  floatx4 acc[2][4];
#pragma unroll
  for (int i = 0; i < 2; i++)
#pragma unroll
    for (int j = 0; j < 4; j++) acc[i][j] = (floatx4)0.f;

  const int srow = tid >> 2, scol = (tid & 3) * 8;
  const bf16* Ap = A + (size_t)(m0 + srow) * K + scol;
  const bf16* Bp = B + (size_t)(n0 + srow) * K + scol;

  auto stage = [&](int k0, int buf) {
    gload16(Ap + k0, (char*)As[buf] + tid * 16);
    gload16(Bp + k0, (char*)Bs[buf] + tid * 16);
    gload16(Bp + (size_t)64 * K + k0, (char*)Bs[buf] + 4096 + tid * 16);
  };
  auto compute = [&](int buf) {
    bf16x8 af[2], bfr[4];
#pragma unroll
    for (int mt = 0; mt < 2; mt++)
      af[mt] = *(const bf16x8*)(&As[buf][(wm + mt * 16 + l16) * 32 + quad * 8]);
#pragma unroll
    for (int nt = 0; nt < 4; nt++)
      bfr[nt] = *(const bf16x8*)(&Bs[buf][(wn + nt * 16 + l16) * 32 + quad * 8]);
#pragma unroll
    for (int mt = 0; mt < 2; mt++)
#pragma unroll
      for (int nt = 0; nt < 4; nt++)
        acc[mt][nt] = MFMA32(af[mt], bfr[nt], acc[mt][nt]);
  };

  stage(0, 0);
  for (int k0 = 0; k0 < K; k0 += 64) {
    __syncthreads();
    if (k0 + 32 < K) stage(k0 + 32, 1);
    compute(0);
    __syncthreads();
    if (k0 + 64 < K) stage(k0 + 64, 0);
    compute(1);
  }

#pragma unroll
  for (int mt = 0; mt < 2; mt++) {
#pragma unroll
    for (int nt = 0; nt < 4; nt++) {
      const int col = n0 + wn + nt * 16 + l16;
      const int row = m0 + wm + mt * 16 + quad * 4;
#pragma unroll
      for (int r = 0; r < 4; r++)
        C[(size_t)(row + r) * N + col] = (TC)acc[mt][nt][r];
    }
  }
}

// Fused K+V projection, split-K x8. A = xb (bf16), B = Wk/Wv (f32 -> bf16).
__global__ __launch_bounds__(256) void kv_gemm(const bf16* __restrict__ xb,
                                               const float* __restrict__ Wk,
                                               const float* __restrict__ Wv,
                                               float* __restrict__ Kf,
                                               float* __restrict__ Vf) {
  __shared__ __align__(16) bf16 As[128 * 40];
  __shared__ __align__(16) bf16 Bs[128 * 40];
  const int tid = threadIdx.x;
  const int wave = tid >> 6, lane = tid & 63;
  const int quad = lane >> 4, l16 = lane & 15;
  const int m0 = blockIdx.y * 128;
  const int kbeg = blockIdx.x * 256, kend = kbeg + 256;
  const int wm = (wave >> 1) * 64, wn = (wave & 1) * 64;

  floatx4 acc[4][4];
#pragma unroll
  for (int i = 0; i < 4; i++)
#pragma unroll
    for (int j = 0; j < 4; j++) acc[i][j] = (floatx4)0.f;

  const int sr = tid >> 2, sc = (tid & 3) * 8;

  for (int k0 = kbeg; k0 < kend; k0 += 32) {
    __syncthreads();
#pragma unroll
    for (int rr = 0; rr < 2; rr++) {
      const int row = sr + rr * 64;
      *(bf16x8*)(&As[row * 40 + sc]) =
          *(const bf16x8*)(&xb[(size_t)(m0 + row) * 2048 + k0 + sc]);
      const float* bsrc = (row < 64) ? &Wk[(size_t)row * 2048 + k0 + sc]
                                     : &Wv[(size_t)(row - 64) * 2048 + k0 + sc];
      *(bf16x8*)(&Bs[row * 40 + sc]) = load8(bsrc);
    }
    __syncthreads();

    bf16x8 af[4], bfr[4];
#pragma unroll
    for (int mt = 0; mt < 4; mt++)
      af[mt] = *(const bf16x8*)(&As[(wm + mt * 16 + l16) * 40 + quad * 8]);
#pragma unroll
    for (int nt = 0; nt < 4; nt++)
      bfr[nt] = *(const bf16x8*)(&Bs[(wn + nt * 16 + l16) * 40 + quad * 8]);
#pragma unroll
    for (int mt = 0; mt < 4; mt++)
#pragma unroll
      for (int nt = 0; nt < 4; nt++)
        acc[mt][nt] = MFMA32(af[mt], bfr[nt], acc[mt][nt]);
  }

#pragma unroll
  for (int mt = 0; mt < 4; mt++) {
#pragma unroll
    for (int nt = 0; nt < 4; nt++) {
      const int col = wn + nt * 16 + l16;
      const int row = m0 + wm + mt * 16 + quad * 4;
      float* dst = (col < 64) ? &Kf[(size_t)row * 64 + col]
                              : &Vf[(size_t)row * 64 + (col - 64)];
#pragma unroll
      for (int r = 0; r < 4; r++) atomicAdd(dst + (size_t)r * 64, acc[mt][nt][r]);
    }
  }
}

// Flash attention, S^T orientation, max-free softmax. LDS-staged K/V (R7:
// global-direct fragment fetch is 3x worse), 512-thread blocks (8 waves share
// each staged tile), grid (16,32)=512 blocks = 2 blocks/CU = 16 waves/CU.
// Balance: co-resident blocks are (c, c+256) [R6-validated round-robin] ->
// by differs by 16 -> t = by<16 ? 15-bx : bx gives complementary q-tiles,
// (2t+2)+(2(15-t)+2)=34 k-iters per CU pair. Double-buffered LDS -> ONE
// barrier per k-tile. Waves skip fully-masked diagonal-overhang tiles.
__global__ __launch_bounds__(512) void attn_kernel(const bf16* __restrict__ Q,
                                                   const bf16* __restrict__ Kb,
                                                   const bf16* __restrict__ Vtb,
                                                   bf16* __restrict__ O) {
  __shared__ __align__(16) bf16 Ks[2][64 * 72];  // [buf][key][d]
  __shared__ __align__(16) bf16 Vt[2][64 * 72];  // [buf][d][key]
  const int tid = threadIdx.x;
  const int wq = tid >> 6;  // wave 0..7 -> q-rows wq*16..wq*16+15
  const int lane = tid & 63;
  const int quad = lane >> 4, l16 = lane & 15;
  const int h = blockIdx.y;
  const int t = (blockIdx.y < 16) ? (15 - blockIdx.x) : blockIdx.x;  // 128-row q-tile
  const float scale2 = 0.125f * 1.44269504f;
  const float slope2 = exp2f(-0.25f * (float)(h + 1)) * 1.44269504f;

  float cq[4];
#pragma unroll
  for (int r = 0; r < 4; r++) cq[r] = slope2 * (float)(quad * 4 + r);
  const float s16 = slope2 * 16.f;
  const bf16x4 ones = {(bf16)1.f, (bf16)1.f, (bf16)1.f, (bf16)1.f};

  const int qi = t * 128 + wq * 16 + l16;  // this lane's query row
  bf16x8 qf[2];
#pragma unroll
  for (int kk = 0; kk < 2; kk++)
    qf[kk] = *(const bf16x8*)(&Q[(size_t)qi * 2048 + h * 64 + kk * 32 + quad * 8]);

  floatx4 oacc[4];
#pragma unroll
  for (int dt = 0; dt < 4; dt++) oacc[dt] = (floatx4)0.f;
  floatx4 lacc = (floatx4)0.f;

  const int r0 = tid >> 3, c0 = (tid & 7) * 8;  // staging: 64 rows x 64 cols
  const int ktmax = 2 * t + 1;
  const int qw0 = t * 128 + wq * 16;  // wave's min q

  bf16x8 kreg = *(const bf16x8*)(&Kb[(size_t)r0 * 64 + c0]);
  bf16x8 vreg = *(const bf16x8*)(&Vtb[(size_t)r0 * 2048 + c0]);

  for (int kt = 0; kt <= ktmax; kt++) {
    const int buf = kt & 1;
    // write buf: waves may still be computing on buf^1 (prev tile) - OK.
    // Overwrite of this buf (kt-2's data) is safe: all reads of it finished
    // before barrier(kt-1), which precedes this write.
    *(bf16x8*)(&Ks[buf][r0 * 72 + c0]) = kreg;
    *(bf16x8*)(&Vt[buf][r0 * 72 + c0]) = vreg;
    __syncthreads();  // tile kt visible
    if (kt < ktmax) {  // prefetch next tile (in flight across compute)
      const int kn = (kt + 1) * 64;
      kreg = *(const bf16x8*)(&Kb[(size_t)(kn + r0) * 64 + c0]);
      vreg = *(const bf16x8*)(&Vtb[(size_t)r0 * 2048 + kn + c0]);
    }
    const int k0 = kt * 64;
    if (k0 > qw0 + 15) continue;  // wave-uniform: fully masked for this wave

    // S^T[key][q] = K · Q^T
    floatx4 s[4];
#pragma unroll
    for (int mt = 0; mt < 4; mt++) s[mt] = (floatx4)0.f;
#pragma unroll
    for (int kk = 0; kk < 2; kk++) {
#pragma unroll
      for (int mt = 0; mt < 4; mt++) {
        bf16x8 kf = *(const bf16x8*)(&Ks[buf][(mt * 16 + l16) * 72 + kk * 32 + quad * 8]);
        s[mt] = MFMA32(kf, qf[kk], s[mt]);
      }
    }

    // p = exp2(s*scale2 + slope2*(j-i)); scores bounded -> no running max
    const float base0 = slope2 * (float)(k0 - qi);
    bf16x4 pb[4];
    if (k0 + 63 <= qw0) {  // interior for the whole wave: no mask
      float base = base0;
#pragma unroll
      for (int mt = 0; mt < 4; mt++) {
        bf16x4 tb;
#pragma unroll
        for (int r = 0; r < 4; r++)
          tb[r] = (bf16)exp2f(__builtin_fmaf(s[mt][r], scale2, base + cq[r]));
        pb[mt] = tb;
        base += s16;
      }
    } else {  // diagonal tile: per-lane causal mask
      const int qloc = qi - k0;
      float base = base0;
#pragma unroll
      for (int mt = 0; mt < 4; mt++) {
        bf16x4 tb;
#pragma unroll
        for (int r = 0; r < 4; r++) {
          const int moff = mt * 16 + quad * 4 + r;
          const float p = exp2f(__builtin_fmaf(s[mt][r], scale2, base + cq[r]));
          tb[r] = (moff <= qloc) ? (bf16)p : (bf16)0.f;
        }
        pb[mt] = tb;
        base += s16;
      }
    }

    // O^T[d][q] += V^T · P^T ; l += 1 · P^T (matrix-pipe row-sum)
#pragma unroll
    for (int mt = 0; mt < 4; mt++) {
      lacc = mfma16(ones, pb[mt], lacc);
#pragma unroll
      for (int dt = 0; dt < 4; dt++) {
        const bf16x4 va =
            *(const bf16x4*)(&Vt[buf][(dt * 16 + l16) * 72 + mt * 16 + quad * 4]);
        oacc[dt] = mfma16(va, pb[mt], oacc[dt]);
      }
    }
  }

  const float linv = 1.0f / lacc[0];
#pragma unroll
  for (int dt = 0; dt < 4; dt++) {
    bf16x4 ob;
#pragma unroll
    for (int r = 0; r < 4; r++) ob[r] = (bf16)(oacc[dt][r] * linv);
    *(bf16x4*)(&O[(size_t)qi * 2048 + h * 64 + dt * 16 + quad * 4]) = ob;
  }
}

extern "C" void kernel_launch(void* const* d_in, const int* in_sizes, int n_in,
                              void* d_out, int out_size, void* d_ws,
                              size_t ws_size, hipStream_t stream) {
  (void)in_sizes; (void)n_in; (void)out_size; (void)ws_size;
  const float* x = (const float*)d_in[0];
  const float* Wq = (const float*)d_in[1];
  const float* Wk = (const float*)d_in[2];
  const float* Wv = (const float*)d_in[3];
  const float* Wo = (const float*)d_in[4];
  float* out = (float*)d_out;

  const size_t NE = (size_t)2048 * 2048;
  bf16* xb = (bf16*)d_ws;              // 8 MB (reused as AO after Q-proj)
  bf16* Wqb = xb + NE;                 // 8 MB
  bf16* Wob = Wqb + NE;                // 8 MB
  bf16* Qb = Wob + NE;                 // 8 MB
  float* Kf = (float*)(Qb + NE);       // 512 KB
  float* Vf = Kf + 2048 * 64;          // 512 KB
  bf16* Kb = (bf16*)(Vf + 2048 * 64);  // 256 KB
  bf16* Vtb = Kb + 2048 * 64;          // 256 KB
  bf16* AO = xb;

  hipMemsetAsync(Kf, 0, 2 * 2048 * 64 * sizeof(float), stream);
  conv3<<<dim3(2048, 3), 256, 0, stream>>>(x, xb, Wq, Wqb, Wo, Wob);
  gemm_bt_a<bf16><<<dim3(16, 32), 256, 0, stream>>>(xb, Wqb, Qb, 2048, 2048, 2048);
  kv_gemm<<<dim3(8, 16), 256, 0, stream>>>(xb, Wk, Wv, Kf, Vf);
  pack_kv<<<512, 256, 0, stream>>>(Kf, Vf, Kb, Vtb);
  attn_kernel<<<dim3(16, 32), 512, 0, stream>>>(Qb, Kb, Vtb, AO);
  gemm_bt_a<float><<<dim3(16, 32), 256, 0, stream>>>(AO, Wob, out, 2048, 2048, 2048);
}